// Round 8
// baseline (312.557 us; speedup 1.0000x reference)
//
#include <hip/hip_runtime.h>
#include <stdint.h>

// RNN: h_{t+1} = tanh(x_t * w_in + h_t @ W_hh^T + (b_ih+b_hh)); out = h_T @ fc_W^T + fc_b
// B = out_size (8192), T = in_sizes[0]/B (4096), H = 10.
//
// R8 design (R7 + trans-queue reduction):
//  * r-recursion: r_t = 1/(1+exp2(a_t)), h = 1-2r; M = -2C*W_hh folded into
//    the MFMA A-operand, W-rowsum folded into bias.
//  * PAIRWISE reciprocal: q01 = rcp(s0*s1); r0 = q01*s1, r1 = q01*s0.
//    4 rcp -> 2 rcp + 6 mul: trans-pipe issue per step drops 64->48 cy,
//    shortening the serial path through the last-packed r.
//  * C-operands for all 8 steps of a block precomputed at block top (pure
//    x-dependent, fills dependency stalls).
//  * One wave = 16 batch elements; mfma_f32_16x16x16f16 D-fragment layout ==
//    B-fragment layout -> the recurrence feeds itself, zero cross-lane ops.
//  * x: 8-step blocks, depth-2 software pipeline.

#define H 10

typedef __fp16 h2 __attribute__((ext_vector_type(2)));
typedef __fp16 h4 __attribute__((ext_vector_type(4)));
typedef float  f4 __attribute__((ext_vector_type(4)));

#if __has_builtin(__builtin_amdgcn_exp2f)
__device__ __forceinline__ float fast_exp2(float x) { return __builtin_amdgcn_exp2f(x); }
#else
__device__ __forceinline__ float fast_exp2(float x) { return __exp2f(x); }
#endif

#if __has_builtin(__builtin_amdgcn_rcpf)
__device__ __forceinline__ float fast_rcp(float x) { return __builtin_amdgcn_rcpf(x); }
#else
__device__ __forceinline__ float fast_rcp(float x) { return 1.0f / x; }
#endif

#if __has_builtin(__builtin_amdgcn_cvt_pkrtz)
__device__ __forceinline__ h2 pk2(float a, float b) { return __builtin_amdgcn_cvt_pkrtz(a, b); }
#else
__device__ __forceinline__ h2 pk2(float a, float b) { h2 r; r.x = (__fp16)a; r.y = (__fp16)b; return r; }
#endif

struct hpair { h2 lo, hi; };
__device__ __forceinline__ h4 mk_h4(h2 lo, h2 hi) {
    hpair p; p.lo = lo; p.hi = hi;
    return __builtin_bit_cast(h4, p);
}

// MFMA wrapper: body guarded by device-compile so BOTH passes see the same
// kernel symbol (R5 lesson: __has_builtin diverges host vs device).
__device__ __forceinline__ f4 mfma_16x16x16f16(h4 a, h4 b, f4 c) {
#if defined(__HIP_DEVICE_COMPILE__)
    return __builtin_amdgcn_mfma_f32_16x16x16f16(a, b, c, 0, 0, 0);
#else
    return c;
#endif
}

// One step of the r-recursion with pairwise rcp. CF4: precomputed C-operand.
#define RNN_STEP(CF4)                                                         \
    do {                                                                      \
        f4 d = mfma_16x16x16f16(m_frag, rb, (CF4));                           \
        float e0 = fast_exp2(d[0]);                                           \
        float e1 = fast_exp2(d[1]);                                           \
        float e2 = fast_exp2(d[2]);                                           \
        float e3 = fast_exp2(d[3]);                                           \
        float s0 = e0 + 1.0f, s1 = e1 + 1.0f;                                 \
        float s2 = e2 + 1.0f, s3 = e3 + 1.0f;                                 \
        float q01 = fast_rcp(s0 * s1);                                        \
        float q23 = fast_rcp(s2 * s3);                                        \
        rf[0] = q01 * s1;  rf[1] = q01 * s0;                                  \
        rf[2] = q23 * s3;  rf[3] = q23 * s2;                                  \
        rb = mk_h4(pk2(rf[0], rf[1]), pk2(rf[2], rf[3]));                     \
    } while (0)

// Precompute 8 C-operands from two float4 x registers (independent of chain).
#define MAKE_C8(V0, V1)                                                       \
    do {                                                                      \
        float xs_[8] = {(V0).x, (V0).y, (V0).z, (V0).w,                       \
                        (V1).x, (V1).y, (V1).z, (V1).w};                      \
        _Pragma("unroll")                                                     \
        for (int s_ = 0; s_ < 8; ++s_) {                                      \
            c8[s_][0] = __builtin_fmaf(xs_[s_], winp[0], biasc[0]);           \
            c8[s_][1] = __builtin_fmaf(xs_[s_], winp[1], biasc[1]);           \
            c8[s_][2] = __builtin_fmaf(xs_[s_], winp[2], biasc[2]);           \
            c8[s_][3] = __builtin_fmaf(xs_[s_], winp[3], biasc[3]);           \
        }                                                                     \
    } while (0)

#define STEP8()                                                               \
    do {                                                                      \
        RNN_STEP(c8[0]); RNN_STEP(c8[1]); RNN_STEP(c8[2]); RNN_STEP(c8[3]);   \
        RNN_STEP(c8[4]); RNN_STEP(c8[5]); RNN_STEP(c8[6]); RNN_STEP(c8[7]);   \
    } while (0)

__global__ __launch_bounds__(64) void rnn_mfma_r2(
    const float* __restrict__ x,
    const float* __restrict__ W_ih,
    const float* __restrict__ W_hh,
    const float* __restrict__ b_ih,
    const float* __restrict__ b_hh,
    const float* __restrict__ fc_W,
    const float* __restrict__ fc_b,
    float* __restrict__ out,
    int B, int T)
{
    const int l = threadIdx.x;    // 0..63 (one wave per block)
    const int n = l & 15;         // batch-within-group; also A-row (unit m)
    const int g = l >> 4;         // k / unit sub-block
    const int b = blockIdx.x * 16 + n;

    const float C = 2.8853900817779268f;  // 2*log2(e)

    // A fragment: M[m][k] = -2*C*W_hh[m][k], fp16. m = n, k = 4g+i.
    h4 m_frag;
#pragma unroll
    for (int i = 0; i < 4; ++i) {
        const int k = 4 * g + i;
        const float w = (n < H && k < H) ? -2.0f * C * W_hh[n * H + k] : 0.0f;
        m_frag[i] = (__fp16)w;
    }

    // Per-lane constants for unit u = 4g+j (dead units -> 0):
    // biasc = C*(b_ih+b_hh + rowsum(W_hh)), winp = C*W_ih, fcw = fc_W.
    float winp[4], biasc[4], fcw[4];
#pragma unroll
    for (int j = 0; j < 4; ++j) {
        const int u = 4 * g + j;
        const bool live = (u < H);
        float rowsum = 0.0f;
        if (live) {
#pragma unroll
            for (int k = 0; k < H; ++k) rowsum += W_hh[u * H + k];
        }
        winp[j]  = live ? C * W_ih[u] : 0.0f;
        biasc[j] = live ? C * (b_ih[u] + b_hh[u] + rowsum) : 0.0f;
        fcw[j]   = live ? fc_W[u] : 0.0f;
    }

    // r = 1/(1+exp2(a)); h=0 <=> r=1/2.
    const __fp16 half16 = (__fp16)0.5f;
    h4 rb = {half16, half16, half16, half16};   // B fragment (fp16 r)
    float rf[4] = {0.5f, 0.5f, 0.5f, 0.5f};    // fp32 r (epilogue)
    f4 c8[8];

    const int brow = (b < B) ? b : (B - 1);
    const float* xr = x + (size_t)brow * (size_t)T;

    // ---- main loop: 8-step blocks, depth-2 pipelined x loads ----
    int t = 0;
    if (((T & 7) == 0) && T >= 24) {
        const int nb = T >> 3;   // number of 8-step blocks (>= 3 here)
        float4 a0 = *(const float4*)(xr + 0);
        float4 a1 = *(const float4*)(xr + 4);
        float4 b0 = *(const float4*)(xr + 8);
        float4 b1 = *(const float4*)(xr + 12);
        for (int blk = 0; blk < nb - 2; ++blk) {
            const float* xf = xr + 8 * (blk + 2);
            float4 f0 = *(const float4*)(xf);
            float4 f1 = *(const float4*)(xf + 4);
            MAKE_C8(a0, a1);
            STEP8();
            a0 = b0; a1 = b1;
            b0 = f0; b1 = f1;
        }
        MAKE_C8(a0, a1);
        STEP8();
        MAKE_C8(b0, b1);
        STEP8();
        t = T;
    }
    for (; t < T; ++t) {          // generic fallback / remainder
        float xq = xr[t];
        f4 cg;
        cg[0] = __builtin_fmaf(xq, winp[0], biasc[0]);
        cg[1] = __builtin_fmaf(xq, winp[1], biasc[1]);
        cg[2] = __builtin_fmaf(xq, winp[2], biasc[2]);
        cg[3] = __builtin_fmaf(xq, winp[3], biasc[3]);
        RNN_STEP(cg);
    }

    // Epilogue: h = 1 - 2r; FC partial over this lane's 4 units, reduce over g.
    float acc = 0.0f;
#pragma unroll
    for (int j = 0; j < 4; ++j) {
        const float h = __builtin_fmaf(-2.0f, rf[j], 1.0f);
        acc = __builtin_fmaf(h, fcw[j], acc);
    }
    acc += __shfl_xor(acc, 16, 64);
    acc += __shfl_xor(acc, 32, 64);
    if (g == 0 && b < B) out[b] = acc + fc_b[0];
}

extern "C" void kernel_launch(void* const* d_in, const int* in_sizes, int n_in,
                              void* d_out, int out_size, void* d_ws, size_t ws_size,
                              hipStream_t stream) {
    const float* x    = (const float*)d_in[0];
    const float* W_ih = (const float*)d_in[1];
    const float* W_hh = (const float*)d_in[2];
    const float* b_ih = (const float*)d_in[3];
    const float* b_hh = (const float*)d_in[4];
    const float* fc_W = (const float*)d_in[5];
    const float* fc_b = (const float*)d_in[6];
    float* out = (float*)d_out;

    const int B = out_size;              // 8192
    const int T = in_sizes[0] / B;       // 4096

    const int blocks = (B + 15) / 16;    // one wave = 16 batch elements
    rnn_mfma_r2<<<blocks, 64, 0, stream>>>(x, W_ih, W_hh, b_ih, b_hh,
                                           fc_W, fc_b, out, B, T);
}